// Round 9
// baseline (374.269 us; speedup 1.0000x reference)
//
#include <hip/hip_runtime.h>
#include <stdint.h>

typedef short v8s __attribute__((ext_vector_type(8)));
typedef short v4s __attribute__((ext_vector_type(4)));
typedef float v4f __attribute__((ext_vector_type(4)));

#define BM 256         // rows per block (8 waves, wave grid 4x2)
#define BN 128
#define BK 64          // k-elements per chunk-pass
#define POS_INF __builtin_inff()

typedef __attribute__((address_space(3))) unsigned int lds_uint;
typedef const __attribute__((address_space(1))) unsigned int glb_uint;

__device__ __forceinline__ void load16_lds(const void* g, void* l) {
    // 16B per lane, LDS dest = wave-uniform base + lane*16
    __builtin_amdgcn_global_load_lds((glb_uint*)g, (lds_uint*)l, 16, 0, 0);
}

__device__ __forceinline__ short f2bf(float f) {
    uint32_t u = __builtin_bit_cast(uint32_t, f);
    u += 0x7fffu + ((u >> 16) & 1u);
    return (short)(u >> 16);
}

// prep: normalize centers rows (fp32 math) -> bf16, pad rows [C, CP) with
// zeros; zero rowblock counters and d_out. x is NOT converted any more --
// the GEMM stages fp32 x directly via DMA and truncation-converts at the
// LDS->register read (saves the 192 MB convert pass).
__global__ void prep(const float* __restrict__ centers,
                     unsigned short* __restrict__ cbf,
                     int C, int D, int CP,
                     int* __restrict__ cnt, int NB,
                     float* __restrict__ out) {
    const int b = blockIdx.x;
    const int t = threadIdx.x;
    if (b == 0 && t == 0) out[0] = 0.0f;
    {
        const int g = b * 256 + t;
        if (g < NB) cnt[g] = 0;
    }
    const int wave = t >> 6, lane = t & 63;
    const int row = b * 4 + wave;
    if (row >= CP) return;
    if (row >= C) {
        v4s z = {0, 0, 0, 0};
        for (int d = lane * 4; d < D; d += 256)
            *(v4s*)&cbf[(size_t)row * D + d] = z;
        return;
    }
    const float* src = centers + (size_t)row * D;
    float ss = 0.0f;
    for (int d = lane * 4; d < D; d += 256) {
        v4f f = *(const v4f*)&src[d];
        ss += f.x * f.x + f.y * f.y + f.z * f.z + f.w * f.w;
    }
    #pragma unroll
    for (int off = 32; off; off >>= 1) ss += __shfl_xor(ss, off, 64);
    const float rn = rsqrtf(ss);
    for (int d = lane * 4; d < D; d += 256) {
        v4f f = *(const v4f*)&src[d];
        v4s s;
        s.x = f2bf(f.x * rn); s.y = f2bf(f.y * rn);
        s.z = f2bf(f.z * rn); s.w = f2bf(f.w * rn);
        *(v4s*)&cbf[(size_t)row * D + d] = s;
    }
}

// Fused GEMM + row-min epilogue + last-block-per-rowblock loss finisher.
// 256x128 block tile, 512 threads = 8 waves (wave grid 4x2, 64x64/wave).
// A staged as RAW FP32 via global_load_lds (64 KB tile); conversion to bf16
// happens at the LDS->reg frag read by truncation (>>16). This keeps the
// async DMA path (round 7 proved manual VGPR staging stalls the k-loop)
// while deleting the 192 MB x-convert prepass.
// LDS: A 64 KB + B 16 KB = 80 KB -> 2 blocks/CU.
// A swizzle (fp32, 16 chunks/row of 16B): slot chunk s of row r holds source
// chunk s ^ (r&15). A-frag read: slot0=(cbase+2q)^l15, slot1=slot0^1 -- per
// quarter-wave a bijection over 16 chunks, only (s,s^8) bank-pair = 2-way
// aliasing = free (m136).
// B (bf16, 8 chunks/row): unchanged proven 0-conflict geometry.
// 1D grid, XCD-swizzled: each XCD runs all NT n-tiles of its row-blocks
// consecutively so the fp32 x-slab (512 KB) is fetched from HBM once.
//
// Cross-block protocol: NO acquire/release fences (agent-scope ACQ_REL RMW
// emits buffer_inv/buffer_wbl2 = per-XCD L2 flush; round 5: +59% k-loop).
// pos/partial use RELAXED agent-scope atomics; __syncthreads drains
// vmcnt(0) before the RELAXED counter RMW; RMW total order + control
// dependency orders the finisher's loads after all 8 writers.
__global__ void __launch_bounds__(512)
gemm_fused(const float* __restrict__ x,
           const unsigned short* __restrict__ cbf,
           const int* __restrict__ labels,
           float* __restrict__ pos, float* __restrict__ partial,
           int* __restrict__ cnt,
           int Bt, int C, int D, int NT, float margin,
           float* __restrict__ out) {
    __shared__ float Af[BM * BK];               // 64 KB (fp32 A tile)
    __shared__ short Bs[BN * BK];               // 16 KB (bf16 B tile)

    const int t   = threadIdx.x;
    const int bid = blockIdx.x;
    const int xcd = bid & 7;
    const int per = bid >> 3;
    const int rowblk = (per >> 3) * 8 + xcd;
    const int nt     = per & 7;
    const int row0 = rowblk * BM;
    const int n0   = nt * BN;

    const int lane = t & 63;
    const int wave = t >> 6;          // 0..7
    const int wm = wave >> 1;         // 0..3 -> m offset wm*64
    const int wn = wave & 1;          // 0..1 -> n offset wn*64
    const int l15 = lane & 15, q = lane >> 4;

    // B staging lane decomposition: 8 rows x 8 chunks(16B) per DMA instr
    const int rsubB = lane >> 3;
    const int csrcB = (lane & 7) ^ rsubB;

    // A staging lane decomposition (fp32): 4 rows x 16 chunks(16B) per instr
    const int rsubA = lane >> 4;             // 0..3

    int myLab = 0;
    if (t < BM) myLab = labels[row0 + t];

    v4f acc[4][4];
    #pragma unroll
    for (int i = 0; i < 4; ++i)
        #pragma unroll
        for (int j = 0; j < 4; ++j)
            acc[i][j] = (v4f){0.f, 0.f, 0.f, 0.f};

    const int KT = D / BK;
    for (int kk = 0; kk < KT; ++kk) {
        const int k0 = kk * BK;
        // stage A tile (fp32): 256 rows x 256 B -> 64 DMA instrs -> 8/wave
        #pragma unroll
        for (int p = 0; p < 8; ++p) {
            const int rbase = wave * 32 + p * 4;
            const int row = rbase + rsubA;
            const int csrc = l15 ^ (row & 15);          // swizzled src chunk
            const float* g = &x[(size_t)(row0 + row) * D + k0 + csrc * 4];
            load16_lds(g, &Af[rbase * BK]);
        }
        // stage B tile (bf16): 128 rows -> 16 DMA instrs -> 2/wave
        #pragma unroll
        for (int p = 0; p < 2; ++p) {
            const int rbase = wave * 16 + p * 8;
            const unsigned short* g =
                &cbf[(size_t)(n0 + rbase + rsubB) * D + k0 + csrcB * 8];
            load16_lds(g, &Bs[rbase * BK]);
        }
        __syncthreads();
        #pragma unroll
        for (int ki = 0; ki < BK; ki += 32) {
            const int cbaseA = ki >> 2;   // fp32 chunk base (0 or 8)
            const int cbaseB = ki >> 3;   // bf16 chunk base (0 or 4)
            v8s a[4], b[4];
            #pragma unroll
            for (int i = 0; i < 4; ++i) {
                const int m = wm * 64 + i * 16 + l15;
                const int slot0 = (cbaseA + 2 * q) ^ l15;   // k-lower 4 floats
                const int slot1 = slot0 ^ 1;                // k-upper 4 floats
                v4f f0 = *(const v4f*)&Af[m * BK + slot0 * 4];
                v4f f1 = *(const v4f*)&Af[m * BK + slot1 * 4];
                // truncation fp32->bf16 (compiler packs via perm/lshr+or)
                unsigned short us[8];
                us[0] = (unsigned short)(__builtin_bit_cast(uint32_t, f0.x) >> 16);
                us[1] = (unsigned short)(__builtin_bit_cast(uint32_t, f0.y) >> 16);
                us[2] = (unsigned short)(__builtin_bit_cast(uint32_t, f0.z) >> 16);
                us[3] = (unsigned short)(__builtin_bit_cast(uint32_t, f0.w) >> 16);
                us[4] = (unsigned short)(__builtin_bit_cast(uint32_t, f1.x) >> 16);
                us[5] = (unsigned short)(__builtin_bit_cast(uint32_t, f1.y) >> 16);
                us[6] = (unsigned short)(__builtin_bit_cast(uint32_t, f1.z) >> 16);
                us[7] = (unsigned short)(__builtin_bit_cast(uint32_t, f1.w) >> 16);
                a[i] = *(v8s*)us;
            }
            #pragma unroll
            for (int j = 0; j < 4; ++j) {
                const int n = wn * 64 + j * 16 + l15;
                b[j] = *(const v8s*)&Bs[n * BK + (((cbaseB + q) ^ (l15 & 7)) * 8)];
            }
            #pragma unroll
            for (int i = 0; i < 4; ++i)
                #pragma unroll
                for (int j = 0; j < 4; ++j)
                    acc[i][j] = __builtin_amdgcn_mfma_f32_16x16x32_bf16(
                        a[i], b[j], acc[i][j], 0, 0, 0);
        }
        __syncthreads();
    }

    // ---- Epilogue (Af/Bs dead; alias scratch) ----
    int*   Ls    = (int*)Af;                           // [BM] (1 KB)
    float* sMinW = (float*)Bs;                         // [2*BM] (2 KB)
    int*   sLast = (int*)((char*)Bs + 2 * BM * 4);     // 1 int
    float* wsum  = (float*)(sLast + 1);                // 8 floats
    if (t < BM) Ls[t] = myLab;
    __syncthreads();

    // dist = 1 - acc; stash pos at label col; row-min over valid cols.
    // C/D layout (16x16x32): col = lane&15, row = q*4 + reg
    #pragma unroll
    for (int i = 0; i < 4; ++i) {
        #pragma unroll
        for (int rg = 0; rg < 4; ++rg) {
            const int row_l = wm * 64 + i * 16 + q * 4 + rg;
            const int lab = Ls[row_l];
            float m = POS_INF;
            #pragma unroll
            for (int j = 0; j < 4; ++j) {
                const int col = n0 + wn * 64 + j * 16 + l15;
                const float d = 1.0f - acc[i][j][rg];
                if (col == lab)
                    __hip_atomic_store(&pos[row0 + row_l], d,
                                       __ATOMIC_RELAXED, __HIP_MEMORY_SCOPE_AGENT);
                else if (col < C) m = fminf(m, d);
            }
            m = fminf(m, __shfl_xor(m, 1, 64));
            m = fminf(m, __shfl_xor(m, 2, 64));
            m = fminf(m, __shfl_xor(m, 4, 64));
            m = fminf(m, __shfl_xor(m, 8, 64));
            if (l15 == 0) sMinW[wn * BM + row_l] = m;
        }
    }
    __syncthreads();
    if (t < BM) {
        const float m = fminf(sMinW[t], sMinW[BM + t]);
        __hip_atomic_store(&partial[(size_t)nt * Bt + row0 + t], m,
                           __ATOMIC_RELAXED, __HIP_MEMORY_SCOPE_AGENT);
    }
    __syncthreads();  // drains vmcnt(0): all sc-bit stores at coherence point

    // Completion counter: RELAXED on purpose (no buffer_inv/buffer_wbl2).
    if (t == 0) {
        __builtin_amdgcn_s_waitcnt(0);  // belt-and-braces; already drained
        const int old = __hip_atomic_fetch_add(&cnt[rowblk], 1,
                                               __ATOMIC_RELAXED,
                                               __HIP_MEMORY_SCOPE_AGENT);
        *sLast = (old == NT - 1);
    }
    __syncthreads();
    if (!*sLast) return;

    float hng = 0.0f;
    if (t < BM) {
        const int r = row0 + t;
        float neg = POS_INF;
        for (int tt = 0; tt < NT; ++tt)
            neg = fminf(neg, __hip_atomic_load(&partial[(size_t)tt * Bt + r],
                                               __ATOMIC_RELAXED,
                                               __HIP_MEMORY_SCOPE_AGENT));
        const float p = __hip_atomic_load(&pos[r], __ATOMIC_RELAXED,
                                          __HIP_MEMORY_SCOPE_AGENT);
        hng = fmaxf(0.0f, p + margin - neg);
    }
    #pragma unroll
    for (int off = 32; off; off >>= 1) hng += __shfl_down(hng, off, 64);
    if (lane == 0) wsum[wave] = hng;
    __syncthreads();
    if (t == 0) {
        float s = 0.0f;
        #pragma unroll
        for (int w = 0; w < 8; ++w) s += wsum[w];
        atomicAdd(out, s * (1.0f / (float)Bt));
    }
}

extern "C" void kernel_launch(void* const* d_in, const int* in_sizes, int n_in,
                              void* d_out, int out_size, void* d_ws, size_t ws_size,
                              hipStream_t stream) {
    const float* x       = (const float*)d_in[0];
    const int*   labels  = (const int*)d_in[1];
    const float* centers = (const float*)d_in[2];
    float* out = (float*)d_out;

    const int Bt = in_sizes[1];           // 65536
    const int D  = in_sizes[0] / Bt;      // 512
    const int C  = in_sizes[2] / D;       // 1000
    const int NT = (C + BN - 1) / BN;     // 8
    const int CP = NT * BN;               // 1024
    const int NB = Bt / BM;               // 256 rowblocks

    char* ws = (char*)d_ws;
    unsigned short* cbf = (unsigned short*)ws;          // CP*D bf16 = 1 MB
    size_t off = (size_t)CP * D * 2;
    off = (off + 255) & ~(size_t)255;
    float* pos = (float*)(ws + off);      off += (size_t)Bt * 4;       // 256 KB
    float* partial = (float*)(ws + off);  off += (size_t)NT * Bt * 4;  // 2 MB
    int* cnt = (int*)(ws + off);

    prep<<<CP / 4, 256, 0, stream>>>(centers, cbf, C, D, CP, cnt, NB, out);

    gemm_fused<<<NB * NT, 512, 0, stream>>>(x, cbf, labels, pos, partial, cnt,
                                            Bt, C, D, NT, 1.0f, out);
}